// Round 2
// baseline (226.857 us; speedup 1.0000x reference)
//
#include <hip/hip_runtime.h>

#define HW_N (512 * 512)          // pixels per image plane
#define BINS 64
#define BPI  64                   // sub-blocks per image; == wave size (pass-2 min/max merge relies on this)
#define TPB  256
#define QPB  ((HW_N / 4) / BPI)   // float4 groups per block per stream = 1024
#define MAXB 16

// Per-block partials from pass 1. 64 B, written with plain stores (no init, no atomics).
struct Part {
    double sum[6];                // x r,g,b ; y r,g,b
    float  mn[2];                 // gray min: [0]=x, [1]=y
    float  mx[2];                 // gray max
};

__device__ __forceinline__ unsigned int f2ord(float f) {
    unsigned int u = __float_as_uint(f);
    return (u & 0x80000000u) ? ~u : (u | 0x80000000u);
}

__device__ __forceinline__ float grayf(float r, float g, float b) {
    return 0.299f * r + 0.587f * g + 0.114f * b;
}

__device__ __forceinline__ double waveSumD(double v) {
#pragma unroll
    for (int o = 32; o > 0; o >>= 1) v += __shfl_down(v, o);
    return v;
}
// xor-butterfly: every lane ends with the reduction result
__device__ __forceinline__ float waveMinAll(float v) {
#pragma unroll
    for (int o = 32; o > 0; o >>= 1) v = fminf(v, __shfl_xor(v, o));
    return v;
}
__device__ __forceinline__ float waveMaxAll(float v) {
#pragma unroll
    for (int o = 32; o > 0; o >>= 1) v = fmaxf(v, __shfl_xor(v, o));
    return v;
}

// ---------------- pass 1: channel sums + gray min/max ----------------
__global__ __launch_bounds__(TPB) void k_pass1(const float* __restrict__ x,
                                               const float* __restrict__ y,
                                               Part* __restrict__ part,
                                               unsigned int* __restrict__ img_hist,
                                               unsigned int* __restrict__ counter) {
    const int tid = threadIdx.x;
    const int blk = blockIdx.x;
    const int b   = blk / BPI;
    const int sub = blk % BPI;

    // init work for pass 2 (visible across the kernel boundary)
    if (sub == 0)
        for (int i = tid; i < 2 * BINS; i += TPB) img_hist[b * 2 * BINS + i] = 0u;
    if (blk == 0 && tid == 0) *counter = 0u;

    const int q0 = sub * QPB;
    const size_t base = (size_t)b * 3 * HW_N;

    const float4* xr = (const float4*)(x + base);
    const float4* xg = (const float4*)(x + base + HW_N);
    const float4* xb = (const float4*)(x + base + 2 * HW_N);
    const float4* yr = (const float4*)(y + base);
    const float4* yg = (const float4*)(y + base + HW_N);
    const float4* yb = (const float4*)(y + base + 2 * HW_N);

    float s0 = 0.f, s1 = 0.f, s2 = 0.f;
    float t0 = 0.f, t1 = 0.f, t2 = 0.f;
    float mnx = 3.4e38f, mxx = -3.4e38f;
    float mny = 3.4e38f, mxy = -3.4e38f;

    for (int i = tid; i < QPB; i += TPB) {
        const int q = q0 + i;
        float4 r = xr[q], g = xg[q], bl = xb[q];
        s0 += (r.x + r.y) + (r.z + r.w);
        s1 += (g.x + g.y) + (g.z + g.w);
        s2 += (bl.x + bl.y) + (bl.z + bl.w);
        {
            float g0 = grayf(r.x, g.x, bl.x), g1 = grayf(r.y, g.y, bl.y);
            float g2 = grayf(r.z, g.z, bl.z), g3 = grayf(r.w, g.w, bl.w);
            mnx = fminf(mnx, fminf(fminf(g0, g1), fminf(g2, g3)));
            mxx = fmaxf(mxx, fmaxf(fmaxf(g0, g1), fmaxf(g2, g3)));
        }
        r = yr[q]; g = yg[q]; bl = yb[q];
        t0 += (r.x + r.y) + (r.z + r.w);
        t1 += (g.x + g.y) + (g.z + g.w);
        t2 += (bl.x + bl.y) + (bl.z + bl.w);
        {
            float g0 = grayf(r.x, g.x, bl.x), g1 = grayf(r.y, g.y, bl.y);
            float g2 = grayf(r.z, g.z, bl.z), g3 = grayf(r.w, g.w, bl.w);
            mny = fminf(mny, fminf(fminf(g0, g1), fminf(g2, g3)));
            mxy = fmaxf(mxy, fmaxf(fmaxf(g0, g1), fmaxf(g2, g3)));
        }
    }

    const int wave = tid >> 6;
    const int lane = tid & 63;
    __shared__ double shs[6][TPB / 64];
    __shared__ float  shmn[2][TPB / 64];
    __shared__ float  shmx[2][TPB / 64];

    double d;
    d = waveSumD((double)s0); if (!lane) shs[0][wave] = d;
    d = waveSumD((double)s1); if (!lane) shs[1][wave] = d;
    d = waveSumD((double)s2); if (!lane) shs[2][wave] = d;
    d = waveSumD((double)t0); if (!lane) shs[3][wave] = d;
    d = waveSumD((double)t1); if (!lane) shs[4][wave] = d;
    d = waveSumD((double)t2); if (!lane) shs[5][wave] = d;
    float f;
    f = waveMinAll(mnx); if (!lane) shmn[0][wave] = f;
    f = waveMinAll(mny); if (!lane) shmn[1][wave] = f;
    f = waveMaxAll(mxx); if (!lane) shmx[0][wave] = f;
    f = waveMaxAll(mxy); if (!lane) shmx[1][wave] = f;
    __syncthreads();

    if (tid == 0) {
        Part& p = part[blk];
        p.sum[0] = shs[0][0] + shs[0][1] + shs[0][2] + shs[0][3];
        p.sum[1] = shs[1][0] + shs[1][1] + shs[1][2] + shs[1][3];
        p.sum[2] = shs[2][0] + shs[2][1] + shs[2][2] + shs[2][3];
        p.sum[3] = shs[3][0] + shs[3][1] + shs[3][2] + shs[3][3];
        p.sum[4] = shs[4][0] + shs[4][1] + shs[4][2] + shs[4][3];
        p.sum[5] = shs[5][0] + shs[5][1] + shs[5][2] + shs[5][3];
        p.mn[0] = fminf(fminf(shmn[0][0], shmn[0][1]), fminf(shmn[0][2], shmn[0][3]));
        p.mn[1] = fminf(fminf(shmn[1][0], shmn[1][1]), fminf(shmn[1][2], shmn[1][3]));
        p.mx[0] = fmaxf(fmaxf(shmx[0][0], shmx[0][1]), fmaxf(shmx[0][2], shmx[0][3]));
        p.mx[1] = fmaxf(fmaxf(shmx[1][0], shmx[1][1]), fmaxf(shmx[1][2], shmx[1][3]));
    }
}

// ---------------- pass 2: histogram + (last block) final loss ----------------
__global__ __launch_bounds__(TPB) void k_pass2(const float* __restrict__ x,
                                               const float* __restrict__ y,
                                               const Part* __restrict__ part,
                                               unsigned int* __restrict__ img_hist,
                                               unsigned int* __restrict__ counter,
                                               float* __restrict__ out, int B) {
    const int tid = threadIdx.x;
    const int blk = blockIdx.x;
    const int b   = blk / BPI;
    const int sub = blk % BPI;
    const int wave = tid >> 6;
    const int lane = tid & 63;

    // image-wide min/max: one Part slot per lane (BPI == 64), xor-butterfly reduce.
    // mn[0],mn[1],mx[0],mx[1] are 16 contiguous bytes at offset 48 of a 64 B struct.
    const float4 mm = *(const float4*)&part[b * BPI + lane].mn[0];
    const float imnx = waveMinAll(mm.x);
    const float imny = waveMinAll(mm.y);
    const float imxx = waveMaxAll(mm.z);
    const float imxy = waveMaxAll(mm.w);
    const float rgx = (imxx > imnx) ? (imxx - imnx) : 1.0f;
    const float rgy = (imxy > imny) ? (imxy - imny) : 1.0f;

    __shared__ unsigned int lh[8][BINS];          // [2 srcs][4 waves][64 bins]
    for (int i = tid; i < 8 * BINS; i += TPB) ((unsigned int*)lh)[i] = 0u;
    __syncthreads();

    const int q0 = sub * QPB;
    const size_t base = (size_t)b * 3 * HW_N;
    const float4* xr = (const float4*)(x + base);
    const float4* xg = (const float4*)(x + base + HW_N);
    const float4* xb = (const float4*)(x + base + 2 * HW_N);
    const float4* yr = (const float4*)(y + base);
    const float4* yg = (const float4*)(y + base + HW_N);
    const float4* yb = (const float4*)(y + base + 2 * HW_N);

    unsigned int* hx = lh[wave];
    unsigned int* hy = lh[4 + wave];

    for (int i = tid; i < QPB; i += TPB) {
        const int q = q0 + i;
        float4 r = xr[q], g = xg[q], bl = xb[q];
        {
            float gv[4] = { grayf(r.x, g.x, bl.x), grayf(r.y, g.y, bl.y),
                            grayf(r.z, g.z, bl.z), grayf(r.w, g.w, bl.w) };
#pragma unroll
            for (int j = 0; j < 4; j++) {
                float t = ((gv[j] - imnx) / rgx) * 63.0f;   // match ref: div, *63, trunc, clip
                int id = (int)t;
                id = id < 0 ? 0 : (id > 63 ? 63 : id);
                atomicAdd(&hx[id], 1u);
            }
        }
        r = yr[q]; g = yg[q]; bl = yb[q];
        {
            float gv[4] = { grayf(r.x, g.x, bl.x), grayf(r.y, g.y, bl.y),
                            grayf(r.z, g.z, bl.z), grayf(r.w, g.w, bl.w) };
#pragma unroll
            for (int j = 0; j < 4; j++) {
                float t = ((gv[j] - imny) / rgy) * 63.0f;
                int id = (int)t;
                id = id < 0 ? 0 : (id > 63 ? 63 : id);
                atomicAdd(&hy[id], 1u);
            }
        }
    }
    __syncthreads();

    // merge 4 wave-hists -> per-image global hist (device-scope atomics, ~64 adds/address)
    for (int i = tid; i < 2 * BINS; i += TPB) {
        const int src = i >> 6, bin = i & 63;
        unsigned int v = lh[src * 4 + 0][bin] + lh[src * 4 + 1][bin] +
                         lh[src * 4 + 2][bin] + lh[src * 4 + 3][bin];
        if (v) atomicAdd(&img_hist[(b * 2 + src) * BINS + bin], v);
    }

    // ---- last-block-done: release, count, last block acquires and finishes ----
    __threadfence();                               // release our hist contributions
    __shared__ unsigned int s_last;
    if (tid == 0) {
        unsigned int old = atomicAdd(counter, 1u);
        s_last = (old == gridDim.x - 1) ? 1u : 0u;
    }
    __syncthreads();
    if (!s_last) return;
    __threadfence();                               // acquire everyone else's writes

    // ---------------- final loss (one block) ----------------
    __shared__ double ssum[MAXB][6];
    __shared__ unsigned int somn[MAXB][2], somx[MAXB][2];
    __shared__ double skl[TPB / 64], scb[TPB / 64];

    // merge channel sums: B*6 = 96 jobs, each sums 64 Part slots
    for (int t = tid; t < B * 6; t += TPB) {
        const int bb = t / 6, k = t - bb * 6;
        double a = 0.0;
#pragma unroll 8
        for (int s = 0; s < BPI; s++) a += part[bb * BPI + s].sum[k];
        ssum[bb][k] = a;
    }
    // per-image min/max validity via LDS atomics on order-preserving encodings
    for (int t = tid; t < MAXB * 2; t += TPB) {
        somn[t >> 1][t & 1] = 0xFFFFFFFFu;
        somx[t >> 1][t & 1] = 0u;
    }
    __syncthreads();
    for (int t = tid; t < B * BPI; t += TPB) {
        const int bb = t >> 6, s = t & 63;
        const Part& p = part[bb * BPI + s];
        atomicMin(&somn[bb][0], f2ord(p.mn[0]));
        atomicMin(&somn[bb][1], f2ord(p.mn[1]));
        atomicMax(&somx[bb][0], f2ord(p.mx[0]));
        atomicMax(&somx[bb][1], f2ord(p.mx[1]));
    }
    __syncthreads();

    const float invN = 1.0f / (float)HW_N;         // 2^-18, exact
    double klt = 0.0, cbt = 0.0;

    // KL: B*BINS = 1024 jobs
    for (int t = tid; t < B * BINS; t += TPB) {
        const int bb = t >> 6, bin = t & 63;
        const bool vldx = somx[bb][0] > somn[bb][0];   // ord encoding is monotonic
        const bool vldy = somx[bb][1] > somn[bb][1];
        const float xh = vldx ? (float)img_hist[(bb * 2 + 0) * BINS + bin] * invN : (1.0f / BINS);
        const float yh = vldy ? (float)img_hist[(bb * 2 + 1) * BINS + bin] * invN : (1.0f / BINS);
        const float log_in = logf(xh + 1e-8f);
        const float ylogy = (yh > 0.0f) ? yh * logf(yh) : 0.0f;
        klt += (double)ylogy - (double)yh * (double)log_in;
    }

    // color balance: B*3 = 48 jobs
    for (int t = tid; t < B * 3; t += TPB) {
        const int bb = t / 3, c = t - bb * 3;
        const double N = (double)HW_N;
        const double xbal = (ssum[bb][c] / N) /
                            ((ssum[bb][0] + ssum[bb][1] + ssum[bb][2]) / N + 1e-8);
        const double ybal = (ssum[bb][3 + c] / N) /
                            ((ssum[bb][3] + ssum[bb][4] + ssum[bb][5]) / N + 1e-8);
        cbt += fabs(xbal - ybal);
    }

    const double kw = waveSumD(klt);
    const double cw = waveSumD(cbt);
    if (!lane) { skl[wave] = kw; scb[wave] = cw; }
    __syncthreads();
    if (tid == 0) {
        double K = 0.0, C = 0.0;
        for (int i = 0; i < TPB / 64; i++) { K += skl[i]; C += scb[i]; }
        const double kl = K / (double)B;
        const double cb = C / (double)(B * 3);
        out[0] = (float)(10.0 * (cb + kl));
    }
}

extern "C" void kernel_launch(void* const* d_in, const int* in_sizes, int n_in,
                              void* d_out, int out_size, void* d_ws, size_t ws_size,
                              hipStream_t stream) {
    const float* x = (const float*)d_in[0];
    const float* y = (const float*)d_in[1];
    float* out = (float*)d_out;
    const int B = in_sizes[0] / (3 * HW_N);   // 16

    Part* part = (Part*)d_ws;                                   // B*BPI*64 B = 64 KiB
    unsigned int* img_hist =
        (unsigned int*)((char*)d_ws + (size_t)B * BPI * sizeof(Part));  // B*2*64*4 = 8 KiB
    unsigned int* counter = img_hist + B * 2 * BINS;

    k_pass1<<<B * BPI, TPB, 0, stream>>>(x, y, part, img_hist, counter);
    k_pass2<<<B * BPI, TPB, 0, stream>>>(x, y, part, img_hist, counter, out, B);
}

// Round 3
// 151.044 us; speedup vs baseline: 1.5019x; 1.5019x over previous
//
#include <hip/hip_runtime.h>

#define HW_N (512 * 512)          // pixels per image plane
#define BINS 64
#define BPI  128                  // sub-blocks per image (2048 blocks total -> 8 blocks/CU)
#define TPB  256
#define QPB  ((HW_N / 4) / BPI)   // float4 groups per block per stream = 512
#define MAXB 16

// Per-block partials from pass 1. 64 B, written with plain stores (no init, no atomics).
struct Part {
    double sum[6];                // x r,g,b ; y r,g,b
    float  mn[2];                 // gray min: [0]=x, [1]=y
    float  mx[2];                 // gray max
};

__device__ __forceinline__ unsigned int f2ord(float f) {
    unsigned int u = __float_as_uint(f);
    return (u & 0x80000000u) ? ~u : (u | 0x80000000u);
}

__device__ __forceinline__ float grayf(float r, float g, float b) {
    return 0.299f * r + 0.587f * g + 0.114f * b;
}

__device__ __forceinline__ double waveSumD(double v) {
#pragma unroll
    for (int o = 32; o > 0; o >>= 1) v += __shfl_down(v, o);
    return v;
}
// xor-butterfly: every lane ends with the reduction result
__device__ __forceinline__ float waveMinAll(float v) {
#pragma unroll
    for (int o = 32; o > 0; o >>= 1) v = fminf(v, __shfl_xor(v, o));
    return v;
}
__device__ __forceinline__ float waveMaxAll(float v) {
#pragma unroll
    for (int o = 32; o > 0; o >>= 1) v = fmaxf(v, __shfl_xor(v, o));
    return v;
}

// ---------------- pass 1: channel sums + gray min/max (+ zero img_hist) ----------------
__global__ __launch_bounds__(TPB) void k_pass1(const float* __restrict__ x,
                                               const float* __restrict__ y,
                                               Part* __restrict__ part,
                                               unsigned int* __restrict__ img_hist) {
    const int tid = threadIdx.x;
    const int blk = blockIdx.x;
    const int b   = blk / BPI;
    const int sub = blk % BPI;

    // zero the per-image global histograms for pass 2 (16 blocks do 128 words each)
    if (sub == 0)
        for (int i = tid; i < 2 * BINS; i += TPB) img_hist[b * 2 * BINS + i] = 0u;

    const int q0 = sub * QPB;
    const size_t base = (size_t)b * 3 * HW_N;

    const float4* xr = (const float4*)(x + base);
    const float4* xg = (const float4*)(x + base + HW_N);
    const float4* xb = (const float4*)(x + base + 2 * HW_N);
    const float4* yr = (const float4*)(y + base);
    const float4* yg = (const float4*)(y + base + HW_N);
    const float4* yb = (const float4*)(y + base + 2 * HW_N);

    float s0 = 0.f, s1 = 0.f, s2 = 0.f;
    float t0 = 0.f, t1 = 0.f, t2 = 0.f;
    float mnx = 3.4e38f, mxx = -3.4e38f;
    float mny = 3.4e38f, mxy = -3.4e38f;

    for (int i = tid; i < QPB; i += TPB) {
        const int q = q0 + i;
        float4 r = xr[q], g = xg[q], bl = xb[q];
        s0 += (r.x + r.y) + (r.z + r.w);
        s1 += (g.x + g.y) + (g.z + g.w);
        s2 += (bl.x + bl.y) + (bl.z + bl.w);
        {
            float g0 = grayf(r.x, g.x, bl.x), g1 = grayf(r.y, g.y, bl.y);
            float g2 = grayf(r.z, g.z, bl.z), g3 = grayf(r.w, g.w, bl.w);
            mnx = fminf(mnx, fminf(fminf(g0, g1), fminf(g2, g3)));
            mxx = fmaxf(mxx, fmaxf(fmaxf(g0, g1), fmaxf(g2, g3)));
        }
        r = yr[q]; g = yg[q]; bl = yb[q];
        t0 += (r.x + r.y) + (r.z + r.w);
        t1 += (g.x + g.y) + (g.z + g.w);
        t2 += (bl.x + bl.y) + (bl.z + bl.w);
        {
            float g0 = grayf(r.x, g.x, bl.x), g1 = grayf(r.y, g.y, bl.y);
            float g2 = grayf(r.z, g.z, bl.z), g3 = grayf(r.w, g.w, bl.w);
            mny = fminf(mny, fminf(fminf(g0, g1), fminf(g2, g3)));
            mxy = fmaxf(mxy, fmaxf(fmaxf(g0, g1), fmaxf(g2, g3)));
        }
    }

    const int wave = tid >> 6;
    const int lane = tid & 63;
    __shared__ double shs[6][TPB / 64];
    __shared__ float  shmn[2][TPB / 64];
    __shared__ float  shmx[2][TPB / 64];

    double d;
    d = waveSumD((double)s0); if (!lane) shs[0][wave] = d;
    d = waveSumD((double)s1); if (!lane) shs[1][wave] = d;
    d = waveSumD((double)s2); if (!lane) shs[2][wave] = d;
    d = waveSumD((double)t0); if (!lane) shs[3][wave] = d;
    d = waveSumD((double)t1); if (!lane) shs[4][wave] = d;
    d = waveSumD((double)t2); if (!lane) shs[5][wave] = d;
    float f;
    f = waveMinAll(mnx); if (!lane) shmn[0][wave] = f;
    f = waveMinAll(mny); if (!lane) shmn[1][wave] = f;
    f = waveMaxAll(mxx); if (!lane) shmx[0][wave] = f;
    f = waveMaxAll(mxy); if (!lane) shmx[1][wave] = f;
    __syncthreads();

    if (tid == 0) {
        Part& p = part[blk];
        p.sum[0] = shs[0][0] + shs[0][1] + shs[0][2] + shs[0][3];
        p.sum[1] = shs[1][0] + shs[1][1] + shs[1][2] + shs[1][3];
        p.sum[2] = shs[2][0] + shs[2][1] + shs[2][2] + shs[2][3];
        p.sum[3] = shs[3][0] + shs[3][1] + shs[3][2] + shs[3][3];
        p.sum[4] = shs[4][0] + shs[4][1] + shs[4][2] + shs[4][3];
        p.sum[5] = shs[5][0] + shs[5][1] + shs[5][2] + shs[5][3];
        p.mn[0] = fminf(fminf(shmn[0][0], shmn[0][1]), fminf(shmn[0][2], shmn[0][3]));
        p.mn[1] = fminf(fminf(shmn[1][0], shmn[1][1]), fminf(shmn[1][2], shmn[1][3]));
        p.mx[0] = fmaxf(fmaxf(shmx[0][0], shmx[0][1]), fmaxf(shmx[0][2], shmx[0][3]));
        p.mx[1] = fmaxf(fmaxf(shmx[1][0], shmx[1][1]), fmaxf(shmx[1][2], shmx[1][3]));
    }
}

// ---------------- pass 2: histograms only (no fence, no counter, no tail) ----------------
__global__ __launch_bounds__(TPB) void k_pass2(const float* __restrict__ x,
                                               const float* __restrict__ y,
                                               const Part* __restrict__ part,
                                               unsigned int* __restrict__ img_hist) {
    const int tid = threadIdx.x;
    const int blk = blockIdx.x;
    const int b   = blk / BPI;
    const int sub = blk % BPI;
    const int wave = tid >> 6;
    const int lane = tid & 63;

    // image-wide min/max: 128 Part slots -> 2 per lane, then xor-butterfly.
    // mn[0],mn[1],mx[0],mx[1] are 16 contiguous bytes at offset 48 of the 64 B struct.
    const Part* pb = part + (size_t)b * BPI;
    const float4 m0 = *(const float4*)&pb[lane].mn[0];
    const float4 m1 = *(const float4*)&pb[lane + 64].mn[0];
    const float imnx = waveMinAll(fminf(m0.x, m1.x));
    const float imny = waveMinAll(fminf(m0.y, m1.y));
    const float imxx = waveMaxAll(fmaxf(m0.z, m1.z));
    const float imxy = waveMaxAll(fmaxf(m0.w, m1.w));
    const float rgx = (imxx > imnx) ? (imxx - imnx) : 1.0f;
    const float rgy = (imxy > imny) ? (imxy - imny) : 1.0f;

    __shared__ unsigned int lh[8][BINS];          // [2 srcs][4 waves][64 bins]
    for (int i = tid; i < 8 * BINS; i += TPB) ((unsigned int*)lh)[i] = 0u;
    __syncthreads();

    const int q0 = sub * QPB;
    const size_t base = (size_t)b * 3 * HW_N;
    const float4* xr = (const float4*)(x + base);
    const float4* xg = (const float4*)(x + base + HW_N);
    const float4* xb = (const float4*)(x + base + 2 * HW_N);
    const float4* yr = (const float4*)(y + base);
    const float4* yg = (const float4*)(y + base + HW_N);
    const float4* yb = (const float4*)(y + base + 2 * HW_N);

    unsigned int* hx = lh[wave];
    unsigned int* hy = lh[4 + wave];

    for (int i = tid; i < QPB; i += TPB) {
        const int q = q0 + i;
        float4 r = xr[q], g = xg[q], bl = xb[q];
        {
            float gv[4] = { grayf(r.x, g.x, bl.x), grayf(r.y, g.y, bl.y),
                            grayf(r.z, g.z, bl.z), grayf(r.w, g.w, bl.w) };
#pragma unroll
            for (int j = 0; j < 4; j++) {
                float t = ((gv[j] - imnx) / rgx) * 63.0f;   // match ref: div, *63, trunc, clip
                int id = (int)t;
                id = id < 0 ? 0 : (id > 63 ? 63 : id);
                atomicAdd(&hx[id], 1u);
            }
        }
        r = yr[q]; g = yg[q]; bl = yb[q];
        {
            float gv[4] = { grayf(r.x, g.x, bl.x), grayf(r.y, g.y, bl.y),
                            grayf(r.z, g.z, bl.z), grayf(r.w, g.w, bl.w) };
#pragma unroll
            for (int j = 0; j < 4; j++) {
                float t = ((gv[j] - imny) / rgy) * 63.0f;
                int id = (int)t;
                id = id < 0 ? 0 : (id > 63 ? 63 : id);
                atomicAdd(&hy[id], 1u);
            }
        }
    }
    __syncthreads();

    // merge 4 wave-hists -> per-image global hist (device-scope atomics, ~128 adds/address)
    for (int i = tid; i < 2 * BINS; i += TPB) {
        const int src = i >> 6, bin = i & 63;
        unsigned int v = lh[src * 4 + 0][bin] + lh[src * 4 + 1][bin] +
                         lh[src * 4 + 2][bin] + lh[src * 4 + 3][bin];
        if (v) atomicAdd(&img_hist[(b * 2 + src) * BINS + bin], v);
    }
}

// ---------------- final: merge partials + loss (1 block; kernel boundary = fence) ----------------
__global__ __launch_bounds__(1024) void k_final(const Part* __restrict__ part,
                                                const unsigned int* __restrict__ img_hist,
                                                float* __restrict__ out, int B) {
    const int tid = threadIdx.x;

    __shared__ double ssum[MAXB][6];
    __shared__ unsigned int somn[MAXB][2], somx[MAXB][2];
    __shared__ double skl[16], scb[16];

    // merge channel sums: B*6 = 96 jobs, each sums BPI Part slots (L2-hot, unrolled for MLP)
    for (int t = tid; t < B * 6; t += 1024) {
        const int bb = t / 6, k = t - bb * 6;
        double a = 0.0;
#pragma unroll 8
        for (int s = 0; s < BPI; s++) a += part[bb * BPI + s].sum[k];
        ssum[bb][k] = a;
    }
    // per-image min/max via LDS atomics on order-preserving encodings
    for (int t = tid; t < MAXB * 2; t += 1024) {
        somn[t >> 1][t & 1] = 0xFFFFFFFFu;
        somx[t >> 1][t & 1] = 0u;
    }
    __syncthreads();
    for (int t = tid; t < B * BPI; t += 1024) {
        const int bb = t / BPI;
        const float4 mm = *(const float4*)&part[t].mn[0];
        atomicMin(&somn[bb][0], f2ord(mm.x));
        atomicMin(&somn[bb][1], f2ord(mm.y));
        atomicMax(&somx[bb][0], f2ord(mm.z));
        atomicMax(&somx[bb][1], f2ord(mm.w));
    }
    __syncthreads();

    const float invN = 1.0f / (float)HW_N;         // 2^-18, exact
    double klt = 0.0, cbt = 0.0;

    // KL: B*BINS = 1024 jobs
    for (int t = tid; t < B * BINS; t += 1024) {
        const int bb = t >> 6, bin = t & 63;
        const bool vldx = somx[bb][0] > somn[bb][0];   // ord encoding is monotonic
        const bool vldy = somx[bb][1] > somn[bb][1];
        const float xh = vldx ? (float)img_hist[(bb * 2 + 0) * BINS + bin] * invN : (1.0f / BINS);
        const float yh = vldy ? (float)img_hist[(bb * 2 + 1) * BINS + bin] * invN : (1.0f / BINS);
        const float log_in = logf(xh + 1e-8f);
        const float ylogy = (yh > 0.0f) ? yh * logf(yh) : 0.0f;
        klt += (double)ylogy - (double)yh * (double)log_in;
    }

    // color balance: B*3 = 48 jobs
    for (int t = tid; t < B * 3; t += 1024) {
        const int bb = t / 3, c = t - bb * 3;
        const double N = (double)HW_N;
        const double xbal = (ssum[bb][c] / N) /
                            ((ssum[bb][0] + ssum[bb][1] + ssum[bb][2]) / N + 1e-8);
        const double ybal = (ssum[bb][3 + c] / N) /
                            ((ssum[bb][3] + ssum[bb][4] + ssum[bb][5]) / N + 1e-8);
        cbt += fabs(xbal - ybal);
    }

    const double kw = waveSumD(klt);
    const double cw = waveSumD(cbt);
    const int wave = tid >> 6, lane = tid & 63;
    if (!lane) { skl[wave] = kw; scb[wave] = cw; }
    __syncthreads();
    if (tid == 0) {
        double K = 0.0, C = 0.0;
        for (int i = 0; i < 16; i++) { K += skl[i]; C += scb[i]; }
        const double kl = K / (double)B;
        const double cb = C / (double)(B * 3);
        out[0] = (float)(10.0 * (cb + kl));
    }
}

extern "C" void kernel_launch(void* const* d_in, const int* in_sizes, int n_in,
                              void* d_out, int out_size, void* d_ws, size_t ws_size,
                              hipStream_t stream) {
    const float* x = (const float*)d_in[0];
    const float* y = (const float*)d_in[1];
    float* out = (float*)d_out;
    const int B = in_sizes[0] / (3 * HW_N);   // 16

    Part* part = (Part*)d_ws;                                   // B*BPI*64 B = 128 KiB
    unsigned int* img_hist =
        (unsigned int*)((char*)d_ws + (size_t)B * BPI * sizeof(Part));  // B*2*64*4 = 8 KiB

    k_pass1<<<B * BPI, TPB, 0, stream>>>(x, y, part, img_hist);
    k_pass2<<<B * BPI, TPB, 0, stream>>>(x, y, part, img_hist);
    k_final<<<1, 1024, 0, stream>>>(part, img_hist, out, B);
}

// Round 4
// 142.663 us; speedup vs baseline: 1.5902x; 1.0587x over previous
//
#include <hip/hip_runtime.h>

#define HW_N (512 * 512)          // pixels per image plane
#define BINS 64
#define BPI  64                   // sub-blocks per image; == wave size (pass-2 min/max merge relies on this)
#define TPB  256
#define QPB  ((HW_N / 4) / BPI)   // float4 groups per block per stream = 1024 (4 loop iters/thread)
#define MAXB 16

// Per-block partials from pass 1. 64 B, written with plain stores (no init, no atomics).
struct Part {
    double sum[6];                // x r,g,b ; y r,g,b
    float  mn[2];                 // gray min: [0]=x, [1]=y
    float  mx[2];                 // gray max
};

__device__ __forceinline__ unsigned int f2ord(float f) {
    unsigned int u = __float_as_uint(f);
    return (u & 0x80000000u) ? ~u : (u | 0x80000000u);
}

__device__ __forceinline__ float grayf(float r, float g, float b) {
    return 0.299f * r + 0.587f * g + 0.114f * b;
}

__device__ __forceinline__ double waveSumD(double v) {
#pragma unroll
    for (int o = 32; o > 0; o >>= 1) v += __shfl_down(v, o);
    return v;
}
// xor-butterfly: every lane ends with the reduction result
__device__ __forceinline__ float waveMinAll(float v) {
#pragma unroll
    for (int o = 32; o > 0; o >>= 1) v = fminf(v, __shfl_xor(v, o));
    return v;
}
__device__ __forceinline__ float waveMaxAll(float v) {
#pragma unroll
    for (int o = 32; o > 0; o >>= 1) v = fmaxf(v, __shfl_xor(v, o));
    return v;
}

// ---- pass 1: channel sums + gray min/max; stores gray planes for pass 2; zeroes img_hist ----
__global__ __launch_bounds__(TPB) void k_pass1(const float* __restrict__ x,
                                               const float* __restrict__ y,
                                               Part* __restrict__ part,
                                               unsigned int* __restrict__ img_hist,
                                               float* __restrict__ gx,
                                               float* __restrict__ gy) {
    const int tid = threadIdx.x;
    const int blk = blockIdx.x;
    const int b   = blk / BPI;
    const int sub = blk % BPI;

    // zero the per-image global histograms for pass 2 (16 blocks do 128 words each)
    if (sub == 0)
        for (int i = tid; i < 2 * BINS; i += TPB) img_hist[b * 2 * BINS + i] = 0u;

    const int q0 = sub * QPB;
    const size_t base = (size_t)b * 3 * HW_N;

    const float4* xr = (const float4*)(x + base);
    const float4* xg = (const float4*)(x + base + HW_N);
    const float4* xb = (const float4*)(x + base + 2 * HW_N);
    const float4* yr = (const float4*)(y + base);
    const float4* yg = (const float4*)(y + base + HW_N);
    const float4* yb = (const float4*)(y + base + 2 * HW_N);
    float4* gxp = (float4*)(gx + (size_t)b * HW_N);
    float4* gyp = (float4*)(gy + (size_t)b * HW_N);

    float s0 = 0.f, s1 = 0.f, s2 = 0.f;
    float t0 = 0.f, t1 = 0.f, t2 = 0.f;
    float mnx = 3.4e38f, mxx = -3.4e38f;
    float mny = 3.4e38f, mxy = -3.4e38f;

    for (int i = tid; i < QPB; i += TPB) {
        const int q = q0 + i;
        float4 r = xr[q], g = xg[q], bl = xb[q];
        s0 += (r.x + r.y) + (r.z + r.w);
        s1 += (g.x + g.y) + (g.z + g.w);
        s2 += (bl.x + bl.y) + (bl.z + bl.w);
        {
            float g0 = grayf(r.x, g.x, bl.x), g1 = grayf(r.y, g.y, bl.y);
            float g2 = grayf(r.z, g.z, bl.z), g3 = grayf(r.w, g.w, bl.w);
            mnx = fminf(mnx, fminf(fminf(g0, g1), fminf(g2, g3)));
            mxx = fmaxf(mxx, fmaxf(fmaxf(g0, g1), fmaxf(g2, g3)));
            gxp[q] = make_float4(g0, g1, g2, g3);   // exact values pass 2 will bin
        }
        r = yr[q]; g = yg[q]; bl = yb[q];
        t0 += (r.x + r.y) + (r.z + r.w);
        t1 += (g.x + g.y) + (g.z + g.w);
        t2 += (bl.x + bl.y) + (bl.z + bl.w);
        {
            float g0 = grayf(r.x, g.x, bl.x), g1 = grayf(r.y, g.y, bl.y);
            float g2 = grayf(r.z, g.z, bl.z), g3 = grayf(r.w, g.w, bl.w);
            mny = fminf(mny, fminf(fminf(g0, g1), fminf(g2, g3)));
            mxy = fmaxf(mxy, fmaxf(fmaxf(g0, g1), fmaxf(g2, g3)));
            gyp[q] = make_float4(g0, g1, g2, g3);
        }
    }

    const int wave = tid >> 6;
    const int lane = tid & 63;
    __shared__ double shs[6][TPB / 64];
    __shared__ float  shmn[2][TPB / 64];
    __shared__ float  shmx[2][TPB / 64];

    double d;
    d = waveSumD((double)s0); if (!lane) shs[0][wave] = d;
    d = waveSumD((double)s1); if (!lane) shs[1][wave] = d;
    d = waveSumD((double)s2); if (!lane) shs[2][wave] = d;
    d = waveSumD((double)t0); if (!lane) shs[3][wave] = d;
    d = waveSumD((double)t1); if (!lane) shs[4][wave] = d;
    d = waveSumD((double)t2); if (!lane) shs[5][wave] = d;
    float f;
    f = waveMinAll(mnx); if (!lane) shmn[0][wave] = f;
    f = waveMinAll(mny); if (!lane) shmn[1][wave] = f;
    f = waveMaxAll(mxx); if (!lane) shmx[0][wave] = f;
    f = waveMaxAll(mxy); if (!lane) shmx[1][wave] = f;
    __syncthreads();

    if (tid == 0) {
        Part& p = part[blk];
        p.sum[0] = shs[0][0] + shs[0][1] + shs[0][2] + shs[0][3];
        p.sum[1] = shs[1][0] + shs[1][1] + shs[1][2] + shs[1][3];
        p.sum[2] = shs[2][0] + shs[2][1] + shs[2][2] + shs[2][3];
        p.sum[3] = shs[3][0] + shs[3][1] + shs[3][2] + shs[3][3];
        p.sum[4] = shs[4][0] + shs[4][1] + shs[4][2] + shs[4][3];
        p.sum[5] = shs[5][0] + shs[5][1] + shs[5][2] + shs[5][3];
        p.mn[0] = fminf(fminf(shmn[0][0], shmn[0][1]), fminf(shmn[0][2], shmn[0][3]));
        p.mn[1] = fminf(fminf(shmn[1][0], shmn[1][1]), fminf(shmn[1][2], shmn[1][3]));
        p.mx[0] = fmaxf(fmaxf(shmx[0][0], shmx[0][1]), fmaxf(shmx[0][2], shmx[0][3]));
        p.mx[1] = fmaxf(fmaxf(shmx[1][0], shmx[1][1]), fmaxf(shmx[1][2], shmx[1][3]));
    }
}

// ---- pass 2: histogram the stored gray planes (32 MB, L2/L3-resident) ----
__global__ __launch_bounds__(TPB) void k_pass2(const float* __restrict__ gx,
                                               const float* __restrict__ gy,
                                               const Part* __restrict__ part,
                                               unsigned int* __restrict__ img_hist) {
    const int tid = threadIdx.x;
    const int blk = blockIdx.x;
    const int b   = blk / BPI;
    const int sub = blk % BPI;
    const int wave = tid >> 6;
    const int lane = tid & 63;

    // image-wide min/max: one Part slot per lane (BPI == 64), xor-butterfly reduce.
    // mn[0],mn[1],mx[0],mx[1] are 16 contiguous bytes at offset 48 of the 64 B struct.
    const float4 mm = *(const float4*)&part[b * BPI + lane].mn[0];
    const float imnx = waveMinAll(mm.x);
    const float imny = waveMinAll(mm.y);
    const float imxx = waveMaxAll(mm.z);
    const float imxy = waveMaxAll(mm.w);
    const float rgx = (imxx > imnx) ? (imxx - imnx) : 1.0f;
    const float rgy = (imxy > imny) ? (imxy - imny) : 1.0f;

    __shared__ unsigned int lh[8][BINS];          // [2 srcs][4 waves][64 bins]
    for (int i = tid; i < 8 * BINS; i += TPB) ((unsigned int*)lh)[i] = 0u;
    __syncthreads();

    const int q0 = sub * QPB;
    const float4* gxp = (const float4*)(gx + (size_t)b * HW_N);
    const float4* gyp = (const float4*)(gy + (size_t)b * HW_N);

    unsigned int* hx = lh[wave];
    unsigned int* hy = lh[4 + wave];

    for (int i = tid; i < QPB; i += TPB) {
        const int q = q0 + i;
        {
            const float4 gv = gxp[q];
            const float g[4] = { gv.x, gv.y, gv.z, gv.w };
#pragma unroll
            for (int j = 0; j < 4; j++) {
                float t = ((g[j] - imnx) / rgx) * 63.0f;    // match ref: div, *63, trunc, clip
                int id = (int)t;
                id = id < 0 ? 0 : (id > 63 ? 63 : id);
                atomicAdd(&hx[id], 1u);
            }
        }
        {
            const float4 gv = gyp[q];
            const float g[4] = { gv.x, gv.y, gv.z, gv.w };
#pragma unroll
            for (int j = 0; j < 4; j++) {
                float t = ((g[j] - imny) / rgy) * 63.0f;
                int id = (int)t;
                id = id < 0 ? 0 : (id > 63 ? 63 : id);
                atomicAdd(&hy[id], 1u);
            }
        }
    }
    __syncthreads();

    // merge 4 wave-hists -> per-image global hist (device-scope atomics, ~64 adds/address)
    for (int i = tid; i < 2 * BINS; i += TPB) {
        const int src = i >> 6, bin = i & 63;
        unsigned int v = lh[src * 4 + 0][bin] + lh[src * 4 + 1][bin] +
                         lh[src * 4 + 2][bin] + lh[src * 4 + 3][bin];
        if (v) atomicAdd(&img_hist[(b * 2 + src) * BINS + bin], v);
    }
}

// ---- final: merge partials + loss (1 block; kernel boundary = the fence) ----
__global__ __launch_bounds__(1024) void k_final(const Part* __restrict__ part,
                                                const unsigned int* __restrict__ img_hist,
                                                float* __restrict__ out, int B) {
    const int tid = threadIdx.x;

    __shared__ double ssum[MAXB][6];
    __shared__ unsigned int somn[MAXB][2], somx[MAXB][2];
    __shared__ double skl[16], scb[16];

    // merge channel sums: B*6 = 96 jobs, each sums BPI Part slots (L2-hot)
    for (int t = tid; t < B * 6; t += 1024) {
        const int bb = t / 6, k = t - bb * 6;
        double a = 0.0;
#pragma unroll 8
        for (int s = 0; s < BPI; s++) a += part[bb * BPI + s].sum[k];
        ssum[bb][k] = a;
    }
    // per-image min/max via LDS atomics on order-preserving encodings
    for (int t = tid; t < MAXB * 2; t += 1024) {
        somn[t >> 1][t & 1] = 0xFFFFFFFFu;
        somx[t >> 1][t & 1] = 0u;
    }
    __syncthreads();
    for (int t = tid; t < B * BPI; t += 1024) {
        const int bb = t / BPI;
        const float4 mm = *(const float4*)&part[t].mn[0];
        atomicMin(&somn[bb][0], f2ord(mm.x));
        atomicMin(&somn[bb][1], f2ord(mm.y));
        atomicMax(&somx[bb][0], f2ord(mm.z));
        atomicMax(&somx[bb][1], f2ord(mm.w));
    }
    __syncthreads();

    const float invN = 1.0f / (float)HW_N;         // 2^-18, exact
    double klt = 0.0, cbt = 0.0;

    // KL: B*BINS = 1024 jobs
    for (int t = tid; t < B * BINS; t += 1024) {
        const int bb = t >> 6, bin = t & 63;
        const bool vldx = somx[bb][0] > somn[bb][0];   // ord encoding is monotonic
        const bool vldy = somx[bb][1] > somn[bb][1];
        const float xh = vldx ? (float)img_hist[(bb * 2 + 0) * BINS + bin] * invN : (1.0f / BINS);
        const float yh = vldy ? (float)img_hist[(bb * 2 + 1) * BINS + bin] * invN : (1.0f / BINS);
        const float log_in = logf(xh + 1e-8f);
        const float ylogy = (yh > 0.0f) ? yh * logf(yh) : 0.0f;
        klt += (double)ylogy - (double)yh * (double)log_in;
    }

    // color balance: B*3 = 48 jobs
    for (int t = tid; t < B * 3; t += 1024) {
        const int bb = t / 3, c = t - bb * 3;
        const double N = (double)HW_N;
        const double xbal = (ssum[bb][c] / N) /
                            ((ssum[bb][0] + ssum[bb][1] + ssum[bb][2]) / N + 1e-8);
        const double ybal = (ssum[bb][3 + c] / N) /
                            ((ssum[bb][3] + ssum[bb][4] + ssum[bb][5]) / N + 1e-8);
        cbt += fabs(xbal - ybal);
    }

    const double kw = waveSumD(klt);
    const double cw = waveSumD(cbt);
    const int wave = tid >> 6, lane = tid & 63;
    if (!lane) { skl[wave] = kw; scb[wave] = cw; }
    __syncthreads();
    if (tid == 0) {
        double K = 0.0, C = 0.0;
        for (int i = 0; i < 16; i++) { K += skl[i]; C += scb[i]; }
        const double kl = K / (double)B;
        const double cb = C / (double)(B * 3);
        out[0] = (float)(10.0 * (cb + kl));
    }
}

extern "C" void kernel_launch(void* const* d_in, const int* in_sizes, int n_in,
                              void* d_out, int out_size, void* d_ws, size_t ws_size,
                              hipStream_t stream) {
    const float* x = (const float*)d_in[0];
    const float* y = (const float*)d_in[1];
    float* out = (float*)d_out;
    const int B = in_sizes[0] / (3 * HW_N);   // 16

    char* ws = (char*)d_ws;
    Part* part = (Part*)ws;                                   // B*BPI*64 B = 64 KiB
    unsigned int* img_hist = (unsigned int*)(ws + (size_t)B * BPI * sizeof(Part)); // 8 KiB
    float* gx = (float*)(ws + (1 << 20));                     // gray planes: 16 MiB each
    float* gy = gx + (size_t)B * HW_N;                        // total ws use ~33 MiB

    k_pass1<<<B * BPI, TPB, 0, stream>>>(x, y, part, img_hist, gx, gy);
    k_pass2<<<B * BPI, TPB, 0, stream>>>(gx, gy, part, img_hist);
    k_final<<<1, 1024, 0, stream>>>(part, img_hist, out, B);
}